// Round 1
// baseline (841.641 us; speedup 1.0000x reference)
//
#include <hip/hip_runtime.h>

#define N_NODES 100000
#define N_EDGES 1600000
#define IN_F    64
#define OUT_F   100

// ==================== node-sorted (NS) path workspace layout ====================
// deg[100K] | offs[100K] | cursor[100K] | gcur | eSorted[1.6M x 64 f32]
#define NS_DEG    0
#define NS_OFFS   (512 * 1024)
#define NS_CUR    (1024 * 1024)
#define NS_GCUR   (1536 * 1024)
#define NS_ESORT  (2 * 1024 * 1024)
#define NS_WS_NEEDED ((size_t)NS_ESORT + (size_t)N_EDGES * IN_F * 4)  // ~411.7 MB

// ==================== legacy bucket-path constants ====================
#define K_BUCKETS 1563            // bucket = dst >> 6  (64 nodes per bucket)
#define NBLK      500             // edge-pass blocks
#define EPB       3200            // edges per block (exact: 500*3200 = 1.6M)
#define SCAN_LEN  (K_BUCKETS * NBLK)            // 781500
#define SCH       2048            // elements per scan block
#define SB        ((SCAN_LEN + SCH - 1) / SCH)  // 382
#define CAP       3072            // LDS sorted-list capacity (avg 1024, +64 sigma)

#define OFF_CNT   0                         // int[SCAN_LEN]  (3.126 MB)
#define OFF_PART  (SCAN_LEN * 4)            // int[SB]
#define OFF_BIN   (SCAN_LEN * 4 + 2048)     // int[N_EDGES]   (6.4 MB)
#define WS_NEEDED (OFF_BIN + N_EDGES * 4)   // 9,528,048

// ---- fallback layout (atomic path, < 8 MB) ----
#define FB_DEG     0
#define FB_OFFS    524288
#define FB_CURSOR  1048576
#define FB_GCUR    1572864
#define FB_EIDS    1573888

// ===================================================================
// ======================= NEW node-sorted path ======================
// ===================================================================

// per-node degree histogram (global atomics; deg is 400KB -> L2-resident)
__global__ void fb_hist(const int* __restrict__ dst, int* __restrict__ deg) {
    int i = (blockIdx.x * blockDim.x + threadIdx.x) * 4;
    if (i + 3 < N_EDGES) {
        int4 d = *(const int4*)(dst + i);
        atomicAdd(&deg[d.x], 1); atomicAdd(&deg[d.y], 1);
        atomicAdd(&deg[d.z], 1); atomicAdd(&deg[d.w], 1);
    } else {
        for (int k = i; k < N_EDGES; k++) atomicAdd(&deg[dst[k]], 1);
    }
}

// exclusive scan of deg -> offs (+cursor copy) via wave scan + atomic carry.
// NOTE: region assignment order is non-deterministic (atomic bs); each node
// still gets a private contiguous region, which is all the gather needs.
__global__ void fb_scan(const int* __restrict__ deg, int* __restrict__ offs,
                        int* __restrict__ cursor, int* __restrict__ gcur) {
    int n = blockIdx.x * blockDim.x + threadIdx.x;
    int lane = threadIdx.x & 63;
    int d = (n < N_NODES) ? deg[n] : 0;
    int x = d;
    #pragma unroll
    for (int off = 1; off < 64; off <<= 1) {
        int y = __shfl_up(x, off, 64);
        if (lane >= off) x += y;
    }
    int excl = x - d;
    int total = __shfl(x, 63, 64);
    int bs = 0;
    if (lane == 63) bs = atomicAdd(gcur, total);
    bs = __shfl(bs, 63, 64);
    if (n < N_NODES) {
        offs[n] = bs + excl;
        cursor[n] = bs + excl;
    }
}

// scatter whole 256B rows of e into node-sorted eSorted.
// Wave layout: sub = lane&15 (float4 column), g = lane>>4 (row within group of 4).
// Reads: 1KB contiguous per wave-load. Writes: 4 x 256B full-line scattered
// (fire-and-forget, no RFO). 8 edges per wave iteration.
__global__ void __launch_bounds__(256) ns_scatter(
        const float* __restrict__ e, const int* __restrict__ dst,
        int* __restrict__ cursor, float* __restrict__ es, int n_waves) {
    int lane = threadIdx.x & 63;
    int wid  = (blockIdx.x * blockDim.x + threadIdx.x) >> 6;
    int sub = lane & 15, g = lane >> 4;
    const float4* e4  = (const float4*)e;
    float4*       es4 = (float4*)es;
    const int EPI = 8;                       // edges per wave-iter
    const int TOT = N_EDGES / EPI;           // 200,000 exact
    for (int it = wid; it < TOT; it += n_waves) {
        int base = it * EPI;
        int p = 0;
        if (lane < EPI) p = atomicAdd(&cursor[dst[base + lane]], 1);
        #pragma unroll
        for (int h = 0; h < 2; h++) {
            int ph = __shfl(p, h * 4 + g, 64);
            float4 v = e4[(size_t)(base + h * 4 + g) * 16 + sub];
            es4[(size_t)ph * 16 + sub] = v;
        }
    }
}

// gather: rows per node are now CONTIGUOUS in eSorted -> fully streaming
// 4KB wave reads. Fused: mean -> srow (LDS) -> GEMV vs W in 128 VGPRs -> out.
__global__ void __launch_bounds__(256, 2) ns_gather(
        const float* __restrict__ es, const int* __restrict__ offs,
        const int* __restrict__ deg, const float* __restrict__ W,
        const float* __restrict__ b, float* __restrict__ out, int n_waves) {
    __shared__ __align__(16) float srow[4][64];
    int lane = threadIdx.x & 63, w = threadIdx.x >> 6;
    int sub = lane & 15, g = lane >> 4;
    int wid  = (blockIdx.x * blockDim.x + threadIdx.x) >> 6;

    int row1 = 64 + lane;
    if (row1 >= OUT_F) row1 = 0;
    float w0[IN_F], w1[IN_F];
    const float4* W4 = (const float4*)W;
    #pragma unroll
    for (int j = 0; j < IN_F / 4; j++) {
        float4 t0 = W4[lane * (IN_F / 4) + j];
        w0[4*j+0] = t0.x; w0[4*j+1] = t0.y; w0[4*j+2] = t0.z; w0[4*j+3] = t0.w;
        float4 t1 = W4[row1 * (IN_F / 4) + j];
        w1[4*j+0] = t1.x; w1[4*j+1] = t1.y; w1[4*j+2] = t1.z; w1[4*j+3] = t1.w;
    }
    float bb0 = b[lane];
    float bb1 = b[row1];

    const float4* es4 = (const float4*)es;
    float* sr = &srow[w][0];

    for (int n = wid; n < N_NODES; n += n_waves) {
        int o = __builtin_amdgcn_readfirstlane(offs[n]);
        int c = __builtin_amdgcn_readfirstlane(deg[n]);
        float h0 = 0.0f, h1 = 0.0f;
        if (c > 0) {
            float4 a0 = {0,0,0,0}, a1 = {0,0,0,0}, a2 = {0,0,0,0}, a3 = {0,0,0,0};
            for (int cb = 0; cb < c; cb += 64) {
                int cc = c - cb; if (cc > 64) cc = 64;
                int ng = (cc + 3) >> 2;          // row groups of 4
                int ob = o + cb;
                for (int i = 0; i < ng; i += 4) {
                    // 4 independent contiguous 1KB loads, branchless masked tail
                    int idx0 = (i + 0) * 4 + g;
                    int idx1 = (i + 1) * 4 + g;
                    int idx2 = (i + 2) * 4 + g;
                    int idx3 = (i + 3) * 4 + g;
                    int c1 = cc - 1;
                    int r0 = ob + ((idx0 < c1) ? idx0 : c1);
                    int r1 = ob + ((idx1 < c1) ? idx1 : c1);
                    int r2 = ob + ((idx2 < c1) ? idx2 : c1);
                    int r3 = ob + ((idx3 < c1) ? idx3 : c1);
                    float4 v0 = es4[(size_t)r0 * 16 + sub];
                    float4 v1 = es4[(size_t)r1 * 16 + sub];
                    float4 v2 = es4[(size_t)r2 * 16 + sub];
                    float4 v3 = es4[(size_t)r3 * 16 + sub];
                    float m0 = (idx0 < cc) ? 1.0f : 0.0f;
                    float m1 = (idx1 < cc) ? 1.0f : 0.0f;
                    float m2 = (idx2 < cc) ? 1.0f : 0.0f;
                    float m3 = (idx3 < cc) ? 1.0f : 0.0f;
                    a0.x = fmaf(v0.x, m0, a0.x); a0.y = fmaf(v0.y, m0, a0.y);
                    a0.z = fmaf(v0.z, m0, a0.z); a0.w = fmaf(v0.w, m0, a0.w);
                    a1.x = fmaf(v1.x, m1, a1.x); a1.y = fmaf(v1.y, m1, a1.y);
                    a1.z = fmaf(v1.z, m1, a1.z); a1.w = fmaf(v1.w, m1, a1.w);
                    a2.x = fmaf(v2.x, m2, a2.x); a2.y = fmaf(v2.y, m2, a2.y);
                    a2.z = fmaf(v2.z, m2, a2.z); a2.w = fmaf(v2.w, m2, a2.w);
                    a3.x = fmaf(v3.x, m3, a3.x); a3.y = fmaf(v3.y, m3, a3.y);
                    a3.z = fmaf(v3.z, m3, a3.z); a3.w = fmaf(v3.w, m3, a3.w);
                }
            }
            float4 s;
            s.x = (a0.x + a1.x) + (a2.x + a3.x);
            s.y = (a0.y + a1.y) + (a2.y + a3.y);
            s.z = (a0.z + a1.z) + (a2.z + a3.z);
            s.w = (a0.w + a1.w) + (a2.w + a3.w);
            s.x += __shfl_xor(s.x, 16, 64);
            s.y += __shfl_xor(s.y, 16, 64);
            s.z += __shfl_xor(s.z, 16, 64);
            s.w += __shfl_xor(s.w, 16, 64);
            s.x += __shfl_xor(s.x, 32, 64);
            s.y += __shfl_xor(s.y, 32, 64);
            s.z += __shfl_xor(s.z, 32, 64);
            s.w += __shfl_xor(s.w, 32, 64);
            float inv = 1.0f / (float)c;
            s.x *= inv; s.y *= inv; s.z *= inv; s.w *= inv;
            if (g == 0) ((float4*)sr)[sub] = s;

            float aa0 = 0.f, aa1 = 0.f;
            const float4* sr4 = (const float4*)sr;
            #pragma unroll
            for (int q = 0; q < 16; q++) {
                float4 f = sr4[q];
                aa0 = fmaf(f.x, w0[4*q+0], aa0);  aa1 = fmaf(f.x, w1[4*q+0], aa1);
                aa0 = fmaf(f.y, w0[4*q+1], aa0);  aa1 = fmaf(f.y, w1[4*q+1], aa1);
                aa0 = fmaf(f.z, w0[4*q+2], aa0);  aa1 = fmaf(f.z, w1[4*q+2], aa1);
                aa0 = fmaf(f.w, w0[4*q+3], aa0);  aa1 = fmaf(f.w, w1[4*q+3], aa1);
            }
            h0 = aa0 + bb0;
            h1 = aa1 + bb1;
        }
        size_t ob2 = (size_t)n * OUT_F;
        out[ob2 + lane] = h0;
        if (lane < OUT_F - 64) out[ob2 + 64 + lane] = h1;
    }
}

// ===================================================================
// ================= legacy bucket path (unchanged) ==================
// ===================================================================

__global__ void __launch_bounds__(256) k_count(const int* __restrict__ dst,
                                               int* __restrict__ cnt) {
    __shared__ int h[K_BUCKETS];
    for (int i = threadIdx.x; i < K_BUCKETS; i += 256) h[i] = 0;
    __syncthreads();
    int base = blockIdx.x * EPB;
    #pragma unroll
    for (int it = 0; it < 3; it++) {
        int i = base + it * 1024 + threadIdx.x * 4;
        int4 d = *(const int4*)(dst + i);
        atomicAdd(&h[d.x >> 6], 1);
        atomicAdd(&h[d.y >> 6], 1);
        atomicAdd(&h[d.z >> 6], 1);
        atomicAdd(&h[d.w >> 6], 1);
    }
    if (threadIdx.x < 128) {
        int i = base + 3072 + threadIdx.x;
        atomicAdd(&h[dst[i] >> 6], 1);
    }
    __syncthreads();
    for (int k = threadIdx.x; k < K_BUCKETS; k += 256)
        cnt[k * NBLK + blockIdx.x] = h[k];
}

__global__ void k_s1(const int* __restrict__ cnt, int* __restrict__ part) {
    __shared__ int ws_[4];
    int b0 = blockIdx.x * SCH;
    int t = threadIdx.x;
    int tot = 0;
    #pragma unroll
    for (int i = 0; i < 8; i++) {
        int idx = b0 + i * 256 + t;
        if (idx < SCAN_LEN) tot += cnt[idx];
    }
    #pragma unroll
    for (int off = 32; off; off >>= 1) tot += __shfl_down(tot, off, 64);
    if ((t & 63) == 0) ws_[t >> 6] = tot;
    __syncthreads();
    if (t == 0) part[blockIdx.x] = ws_[0] + ws_[1] + ws_[2] + ws_[3];
}

__global__ void k_s2(int* __restrict__ part) {
    int lane = threadIdx.x;
    int carry = 0;
    for (int b0 = 0; b0 < SB; b0 += 64) {
        int idx = b0 + lane;
        int v = (idx < SB) ? part[idx] : 0;
        int x = v;
        #pragma unroll
        for (int off = 1; off < 64; off <<= 1) {
            int y = __shfl_up(x, off, 64);
            if (lane >= off) x += y;
        }
        int tot = __shfl(x, 63, 64);
        if (idx < SB) part[idx] = carry + x - v;
        carry += tot;
    }
}

__global__ void k_s3(int* __restrict__ cnt, const int* __restrict__ part) {
    __shared__ int wsum[4];
    int t = threadIdx.x, lane = t & 63, w = t >> 6;
    int idx0 = blockIdx.x * SCH + t * 8;
    int v[8];
    int s = 0;
    #pragma unroll
    for (int i = 0; i < 8; i++) {
        v[i] = (idx0 + i < SCAN_LEN) ? cnt[idx0 + i] : 0;
        s += v[i];
    }
    int x = s;
    #pragma unroll
    for (int off = 1; off < 64; off <<= 1) {
        int y = __shfl_up(x, off, 64);
        if (lane >= off) x += y;
    }
    if (lane == 63) wsum[w] = x;
    __syncthreads();
    int wb = 0;
    for (int i = 0; i < w; i++) wb += wsum[i];
    int run = part[blockIdx.x] + wb + (x - s);
    #pragma unroll
    for (int i = 0; i < 8; i++) {
        int tmp = v[i];
        if (idx0 + i < SCAN_LEN) cnt[idx0 + i] = run;
        run += tmp;
    }
}

__global__ void __launch_bounds__(256) k_bin(const int* __restrict__ dst,
                                             const int* __restrict__ scn,
                                             int* __restrict__ binned) {
    __shared__ int cur[K_BUCKETS];
    for (int k = threadIdx.x; k < K_BUCKETS; k += 256)
        cur[k] = scn[k * NBLK + blockIdx.x];
    __syncthreads();
    int base = blockIdx.x * EPB;
    #pragma unroll
    for (int it = 0; it < 3; it++) {
        int i = base + it * 1024 + threadIdx.x * 4;
        int4 d = *(const int4*)(dst + i);
        int p;
        p = atomicAdd(&cur[d.x >> 6], 1); binned[p] = ((d.x & 63) << 21) | i;
        p = atomicAdd(&cur[d.y >> 6], 1); binned[p] = ((d.y & 63) << 21) | (i + 1);
        p = atomicAdd(&cur[d.z >> 6], 1); binned[p] = ((d.z & 63) << 21) | (i + 2);
        p = atomicAdd(&cur[d.w >> 6], 1); binned[p] = ((d.w & 63) << 21) | (i + 3);
    }
    if (threadIdx.x < 128) {
        int i = base + 3072 + threadIdx.x;
        int d = dst[i];
        int p = atomicAdd(&cur[d >> 6], 1);
        binned[p] = ((d & 63) << 21) | i;
    }
}

__global__ void __launch_bounds__(256, 2) k_fused(
        const float* __restrict__ e, const int* __restrict__ binned,
        const int* __restrict__ scn, const float* __restrict__ W,
        const float* __restrict__ b, float* __restrict__ out) {
    __shared__ int   deg[64];
    __shared__ int   lofs[64];
    __shared__ int   sorted[CAP];
    __shared__ __align__(16) float srow[4][64];

    int tid = threadIdx.x, lane = tid & 63, w = tid >> 6;
    int sub = lane & 15, g = lane >> 4;
    int bk = blockIdx.x;
    int base = scn[bk * NBLK];
    int end  = (bk + 1 < K_BUCKETS) ? scn[(bk + 1) * NBLK] : N_EDGES;
    int cntb = end - base;

    for (int i = tid; i < 64; i += 256) deg[i] = 0;
    __syncthreads();

    bool fast = (cntb <= CAP);
    if (fast) {
        int pk[12], rk[12];
        int nI = (cntb + 255) >> 8;
        for (int i = 0; i < nI; i++) {
            int idx = tid + i * 256;
            if (idx < cntb) {
                int p = binned[base + idx];
                pk[i] = p;
                rk[i] = atomicAdd(&deg[p >> 21], 1);
            } else pk[i] = -1;
        }
        __syncthreads();
        if (w == 0) {
            int d = deg[lane];
            int x = d;
            #pragma unroll
            for (int off = 1; off < 64; off <<= 1) {
                int y = __shfl_up(x, off, 64);
                if (lane >= off) x += y;
            }
            lofs[lane] = x - d;
        }
        __syncthreads();
        for (int i = 0; i < nI; i++) {
            if (pk[i] >= 0) {
                int lid = pk[i] >> 21;
                sorted[lofs[lid] + rk[i]] = pk[i] & 0x1FFFFF;
            }
        }
        __syncthreads();
    }

    int row1 = 64 + lane;
    if (row1 >= OUT_F) row1 = 0;
    float w0[IN_F], w1[IN_F];
    const float4* W4 = (const float4*)W;
    #pragma unroll
    for (int j = 0; j < IN_F / 4; j++) {
        float4 t0 = W4[lane * (IN_F / 4) + j];
        w0[4*j+0] = t0.x; w0[4*j+1] = t0.y; w0[4*j+2] = t0.z; w0[4*j+3] = t0.w;
        float4 t1 = W4[row1 * (IN_F / 4) + j];
        w1[4*j+0] = t1.x; w1[4*j+1] = t1.y; w1[4*j+2] = t1.z; w1[4*j+3] = t1.w;
    }
    float bb0 = b[lane];
    float bb1 = b[row1];

    const float4* e4 = (const float4*)e;

    for (int t = 0; t < 16; t++) {
        int lid = w * 16 + t;
        int node = bk * 64 + lid;
        if (node >= N_NODES) break;

        int c;
        float* sr = &srow[w][0];

        if (fast) {
            int o = lofs[lid];
            c = deg[lid];
            if (c > 0) {
                float4 a0 = {0,0,0,0}, a1 = {0,0,0,0}, a2 = {0,0,0,0}, a3 = {0,0,0,0};
                for (int cb = 0; cb < c; cb += 64) {
                    int cc = c - cb; if (cc > 64) cc = 64;
                    int ng = (cc + 3) >> 2;
                    int ob = o + cb;
                    for (int i = 0; i < ng; i += 4) {
                        int idx0 = (i + 0) * 4 + g;
                        int idx1 = (i + 1) * 4 + g;
                        int idx2 = (i + 2) * 4 + g;
                        int idx3 = (i + 3) * 4 + g;
                        int c1 = cc - 1;
                        int e0 = sorted[ob + ((idx0 < c1) ? idx0 : c1)];
                        int e1 = sorted[ob + ((idx1 < c1) ? idx1 : c1)];
                        int e2 = sorted[ob + ((idx2 < c1) ? idx2 : c1)];
                        int e3 = sorted[ob + ((idx3 < c1) ? idx3 : c1)];
                        float4 v0 = e4[(size_t)e0 * 16 + sub];
                        float4 v1 = e4[(size_t)e1 * 16 + sub];
                        float4 v2 = e4[(size_t)e2 * 16 + sub];
                        float4 v3 = e4[(size_t)e3 * 16 + sub];
                        float m0 = (idx0 < cc) ? 1.0f : 0.0f;
                        float m1 = (idx1 < cc) ? 1.0f : 0.0f;
                        float m2 = (idx2 < cc) ? 1.0f : 0.0f;
                        float m3 = (idx3 < cc) ? 1.0f : 0.0f;
                        a0.x = fmaf(v0.x, m0, a0.x); a0.y = fmaf(v0.y, m0, a0.y);
                        a0.z = fmaf(v0.z, m0, a0.z); a0.w = fmaf(v0.w, m0, a0.w);
                        a1.x = fmaf(v1.x, m1, a1.x); a1.y = fmaf(v1.y, m1, a1.y);
                        a1.z = fmaf(v1.z, m1, a1.z); a1.w = fmaf(v1.w, m1, a1.w);
                        a2.x = fmaf(v2.x, m2, a2.x); a2.y = fmaf(v2.y, m2, a2.y);
                        a2.z = fmaf(v2.z, m2, a2.z); a2.w = fmaf(v2.w, m2, a2.w);
                        a3.x = fmaf(v3.x, m3, a3.x); a3.y = fmaf(v3.y, m3, a3.y);
                        a3.z = fmaf(v3.z, m3, a3.z); a3.w = fmaf(v3.w, m3, a3.w);
                    }
                }
                float4 s;
                s.x = (a0.x + a1.x) + (a2.x + a3.x);
                s.y = (a0.y + a1.y) + (a2.y + a3.y);
                s.z = (a0.z + a1.z) + (a2.z + a3.z);
                s.w = (a0.w + a1.w) + (a2.w + a3.w);
                s.x += __shfl_xor(s.x, 16, 64);
                s.y += __shfl_xor(s.y, 16, 64);
                s.z += __shfl_xor(s.z, 16, 64);
                s.w += __shfl_xor(s.w, 16, 64);
                s.x += __shfl_xor(s.x, 32, 64);
                s.y += __shfl_xor(s.y, 32, 64);
                s.z += __shfl_xor(s.z, 32, 64);
                s.w += __shfl_xor(s.w, 32, 64);
                float inv = 1.0f / (float)c;
                s.x *= inv; s.y *= inv; s.z *= inv; s.w *= inv;
                if (g == 0) ((float4*)sr)[sub] = s;
            }
        } else {
            c = 0;
            float s0 = 0.f;
            for (int j0 = 0; j0 < cntb; j0 += 64) {
                int idx = j0 + lane;
                int p = (idx < cntb) ? binned[base + idx] : -1;
                bool m = (p >= 0) && ((p >> 21) == lid);
                unsigned long long msk = __ballot(m);
                c += __popcll(msk);
                while (msk) {
                    int l = __ffsll((long long)msk) - 1;
                    msk &= msk - 1;
                    int eid = __builtin_amdgcn_readlane(p, l) & 0x1FFFFF;
                    s0 += e[((size_t)eid << 6) + lane];
                }
            }
            if (c > 0) sr[lane] = s0 * (1.0f / (float)c);
        }

        float h0 = 0.0f, h1 = 0.0f;
        if (c > 0) {
            float aa0 = 0.f, aa1 = 0.f;
            const float4* sr4 = (const float4*)sr;
            #pragma unroll
            for (int q = 0; q < 16; q++) {
                float4 f = sr4[q];
                aa0 = fmaf(f.x, w0[4*q+0], aa0);  aa1 = fmaf(f.x, w1[4*q+0], aa1);
                aa0 = fmaf(f.y, w0[4*q+1], aa0);  aa1 = fmaf(f.y, w1[4*q+1], aa1);
                aa0 = fmaf(f.z, w0[4*q+2], aa0);  aa1 = fmaf(f.z, w1[4*q+2], aa1);
                aa0 = fmaf(f.w, w0[4*q+3], aa0);  aa1 = fmaf(f.w, w1[4*q+3], aa1);
            }
            h0 = aa0 + bb0;
            h1 = aa1 + bb1;
        }

        size_t ob2 = (size_t)node * OUT_F;
        out[ob2 + lane] = h0;
        if (lane < OUT_F - 64) out[ob2 + 64 + lane] = h1;
    }
}

// ===================== legacy atomic fallback =====================
__global__ void fb_scatter(const int* __restrict__ dst, int* __restrict__ cursor,
                           int* __restrict__ eids) {
    int i = (blockIdx.x * blockDim.x + threadIdx.x) * 4;
    if (i + 3 < N_EDGES) {
        int4 d = *(const int4*)(dst + i);
        int p0 = atomicAdd(&cursor[d.x], 1);
        int p1 = atomicAdd(&cursor[d.y], 1);
        int p2 = atomicAdd(&cursor[d.z], 1);
        int p3 = atomicAdd(&cursor[d.w], 1);
        eids[p0] = i; eids[p1] = i + 1; eids[p2] = i + 2; eids[p3] = i + 3;
    } else {
        for (int k = i; k < N_EDGES; k++) {
            int pos = atomicAdd(&cursor[dst[k]], 1);
            eids[pos] = k;
        }
    }
}

__global__ void __launch_bounds__(256) fb_gather(
        const float* __restrict__ e, const int* __restrict__ eids,
        const int* __restrict__ offs, const int* __restrict__ deg,
        const float* __restrict__ W, const float* __restrict__ b,
        float* __restrict__ out, int n_waves_total) {
    __shared__ float srow[4][64];
    int lane = threadIdx.x & 63, w = (threadIdx.x >> 6) & 3;
    int wid  = (blockIdx.x * blockDim.x + threadIdx.x) >> 6;
    int row1 = 64 + lane;
    if (row1 >= OUT_F) row1 = 0;
    float w0[IN_F], w1[IN_F];
    const float4* W4 = (const float4*)W;
    #pragma unroll
    for (int j = 0; j < IN_F / 4; j++) {
        float4 t0 = W4[lane * (IN_F / 4) + j];
        w0[4*j+0] = t0.x; w0[4*j+1] = t0.y; w0[4*j+2] = t0.z; w0[4*j+3] = t0.w;
        float4 t1 = W4[row1 * (IN_F / 4) + j];
        w1[4*j+0] = t1.x; w1[4*j+1] = t1.y; w1[4*j+2] = t1.z; w1[4*j+3] = t1.w;
    }
    float bb0 = b[lane];
    float bb1 = b[row1];
    for (int n = wid; n < N_NODES; n += n_waves_total) {
        int o = __builtin_amdgcn_readfirstlane(offs[n]);
        int c = __builtin_amdgcn_readfirstlane(deg[n]);
        float s0 = 0.f, s1 = 0.f;
        for (int cb = 0; cb < c; cb += 64) {
            int cc = c - cb; if (cc > 64) cc = 64;
            int myeid = 0;
            if (lane < cc) myeid = eids[o + cb + lane];
            for (int j = 0; j < cc; j += 2) {
                int i0 = __builtin_amdgcn_readlane(myeid, j);
                s0 += e[((size_t)i0 << 6) + lane];
                if (j + 1 < cc) {
                    int i1 = __builtin_amdgcn_readlane(myeid, j + 1);
                    s1 += e[((size_t)i1 << 6) + lane];
                }
            }
        }
        float* sr = &srow[w][0];
        sr[lane] = (s0 + s1) * ((c > 0) ? 1.0f / (float)c : 0.0f);
        float a0 = 0.f, a1 = 0.f;
        const float4* sr4 = (const float4*)sr;
        #pragma unroll
        for (int q = 0; q < 16; q++) {
            float4 f = sr4[q];
            a0 = fmaf(f.x, w0[4*q+0], a0);  a1 = fmaf(f.x, w1[4*q+0], a1);
            a0 = fmaf(f.y, w0[4*q+1], a0);  a1 = fmaf(f.y, w1[4*q+1], a1);
            a0 = fmaf(f.z, w0[4*q+2], a0);  a1 = fmaf(f.z, w1[4*q+2], a1);
            a0 = fmaf(f.w, w0[4*q+3], a0);  a1 = fmaf(f.w, w1[4*q+3], a1);
        }
        float h0 = (c > 0) ? a0 + bb0 : 0.0f;
        float h1 = (c > 0) ? a1 + bb1 : 0.0f;
        size_t ob = (size_t)n * OUT_F;
        out[ob + lane] = h0;
        if (lane < OUT_F - 64) out[ob + 64 + lane] = h1;
    }
}

extern "C" void kernel_launch(void* const* d_in, const int* in_sizes, int n_in,
                              void* d_out, int out_size, void* d_ws, size_t ws_size,
                              hipStream_t stream) {
    const float* e   = (const float*)d_in[0];
    const int*   dst = (const int*)d_in[1];
    const float* W   = (const float*)d_in[2];
    const float* b   = (const float*)d_in[3];
    float* out = (float*)d_out;
    char* ws = (char*)d_ws;

    if (ws_size >= NS_WS_NEEDED) {
        // ---- node-sorted streaming path ----
        int*   deg    = (int*)(ws + NS_DEG);
        int*   offs   = (int*)(ws + NS_OFFS);
        int*   cursor = (int*)(ws + NS_CUR);
        int*   gcur   = (int*)(ws + NS_GCUR);
        float* es     = (float*)(ws + NS_ESORT);

        hipMemsetAsync(deg, 0, N_NODES * sizeof(int), stream);
        hipMemsetAsync(gcur, 0, sizeof(int), stream);
        fb_hist   <<<(N_EDGES / 4 + 255) / 256, 256, 0, stream>>>(dst, deg);
        fb_scan   <<<(N_NODES + 255) / 256, 256, 0, stream>>>(deg, offs, cursor, gcur);
        ns_scatter<<<2048, 256, 0, stream>>>(e, dst, cursor, es, 2048 * 4);
        ns_gather <<<2048, 256, 0, stream>>>(es, offs, deg, W, b, out, 2048 * 4);
    } else if (ws_size >= (size_t)WS_NEEDED) {
        // ---- legacy bucket path ----
        int* cnt    = (int*)(ws + OFF_CNT);
        int* part   = (int*)(ws + OFF_PART);
        int* binned = (int*)(ws + OFF_BIN);

        k_count<<<NBLK, 256, 0, stream>>>(dst, cnt);
        k_s1   <<<SB, 256, 0, stream>>>(cnt, part);
        k_s2   <<<1, 64, 0, stream>>>(part);
        k_s3   <<<SB, 256, 0, stream>>>(cnt, part);
        k_bin  <<<NBLK, 256, 0, stream>>>(dst, cnt, binned);
        k_fused<<<K_BUCKETS, 256, 0, stream>>>(e, binned, cnt, W, b, out);
    } else {
        // ---- legacy atomic fallback ----
        int* deg    = (int*)(ws + FB_DEG);
        int* offs   = (int*)(ws + FB_OFFS);
        int* cursor = (int*)(ws + FB_CURSOR);
        int* gcur   = (int*)(ws + FB_GCUR);
        int* eids   = (int*)(ws + FB_EIDS);

        hipMemsetAsync(deg, 0, N_NODES * sizeof(int), stream);
        hipMemsetAsync(gcur, 0, sizeof(int), stream);
        fb_hist   <<<(N_EDGES / 4 + 255) / 256, 256, 0, stream>>>(dst, deg);
        fb_scan   <<<(N_NODES + 255) / 256, 256, 0, stream>>>(deg, offs, cursor, gcur);
        fb_scatter<<<(N_EDGES / 4 + 255) / 256, 256, 0, stream>>>(dst, cursor, eids);
        fb_gather <<<8192, 256, 0, stream>>>(e, eids, offs, deg, W, b, out, 8192 * 4);
    }
}

// Round 2
// 825.704 us; speedup vs baseline: 1.0193x; 1.0193x over previous
//
#include <hip/hip_runtime.h>

#define N_NODES 100000
#define N_EDGES 1600000
#define IN_F    64
#define OUT_F   100

// ---- workspace layout (bytes) ----
#define WS_DEG     0                       // int[N_NODES]
#define WS_OFFS    (512 * 1024)            // int[N_NODES]
#define WS_CUR     (1024 * 1024)           // int[N_NODES]
#define WS_GCUR    (1536 * 1024)           // int[1]
#define WS_EIDS    1573888                 // int[N_EDGES]
#define WS_NEEDED  ((size_t)WS_EIDS + (size_t)N_EDGES * 4)   // ~8 MB

// ===================== per-node degree histogram =====================
// 1.6M int atomics into a 400KB L2-resident array; reads dst coalesced.
__global__ void k_hist(const int* __restrict__ dst, int* __restrict__ deg) {
    int i = (blockIdx.x * blockDim.x + threadIdx.x) * 4;
    if (i + 3 < N_EDGES) {
        int4 d = *(const int4*)(dst + i);
        atomicAdd(&deg[d.x], 1); atomicAdd(&deg[d.y], 1);
        atomicAdd(&deg[d.z], 1); atomicAdd(&deg[d.w], 1);
    } else {
        for (int k = i; k < N_EDGES; k++) atomicAdd(&deg[dst[k]], 1);
    }
}

// ===================== exclusive scan (wave scan + atomic carry) =====================
// Region bases are non-monotonic across 64-node groups (atomic carry), but each
// node gets a private contiguous [offs[n], offs[n]+deg[n]) region, and within a
// 64-aligned node group offs IS contiguous — the gather only relies on the former.
__global__ void k_scan(const int* __restrict__ deg, int* __restrict__ offs,
                       int* __restrict__ cursor, int* __restrict__ gcur) {
    int n = blockIdx.x * blockDim.x + threadIdx.x;
    int lane = threadIdx.x & 63;
    int d = (n < N_NODES) ? deg[n] : 0;
    int x = d;
    #pragma unroll
    for (int off = 1; off < 64; off <<= 1) {
        int y = __shfl_up(x, off, 64);
        if (lane >= off) x += y;
    }
    int excl = x - d;
    int total = __shfl(x, 63, 64);
    int bs = 0;
    if (lane == 63) bs = atomicAdd(gcur, total);
    bs = __shfl(bs, 63, 64);
    if (n < N_NODES) {
        offs[n] = bs + excl;
        cursor[n] = bs + excl;
    }
}

// ===================== scatter edge ids into node-grouped order =====================
__global__ void k_scat(const int* __restrict__ dst, int* __restrict__ cursor,
                       int* __restrict__ eids) {
    int i = (blockIdx.x * blockDim.x + threadIdx.x) * 4;
    if (i + 3 < N_EDGES) {
        int4 d = *(const int4*)(dst + i);
        int p0 = atomicAdd(&cursor[d.x], 1);
        int p1 = atomicAdd(&cursor[d.y], 1);
        int p2 = atomicAdd(&cursor[d.z], 1);
        int p3 = atomicAdd(&cursor[d.w], 1);
        eids[p0] = i; eids[p1] = i + 1; eids[p2] = i + 2; eids[p3] = i + 3;
    } else {
        for (int k = i; k < N_EDGES; k++) {
            int pos = atomicAdd(&cursor[dst[k]], 1);
            eids[pos] = k;
        }
    }
}

// ===================== fused gather + mean + GEMV =====================
// One wave per 16 consecutive nodes. Per node: edge ids come from one coalesced
// 64-wide eids load (next node's chunk prefetched), broadcast to the 4 lane
// groups via __shfl (bpermute). Gather uses the float4 group layout: lane =
// (g=lane>>4, sub=lane&15); one wave-load covers FOUR edge rows (64 x 16B =
// 1KB), 4 independent loads in flight, branchless masked-FMA tail. Cross-group
// reduce = 8 shfl_xor. GEMV against W held in 128 VGPRs, via 16 b128 LDS
// broadcasts of the mean row. No block barriers anywhere.
#define NPW 16     // nodes per wave
__global__ void __launch_bounds__(256, 2) k_gather(
        const float* __restrict__ e, const int* __restrict__ eids,
        const int* __restrict__ offs, const int* __restrict__ deg,
        const float* __restrict__ W, const float* __restrict__ b,
        float* __restrict__ out) {
    __shared__ __align__(16) float srow[4][64];
    int lane = threadIdx.x & 63, w = threadIdx.x >> 6;
    int sub = lane & 15, g = lane >> 4;
    int wave = blockIdx.x * 4 + w;
    int base = wave * NPW;
    if (base >= N_NODES) return;
    int nmax = N_NODES - base;
    if (nmax > NPW) nmax = NPW;

    // W rows into registers (lane -> row lane and row 64+lane)
    int row1 = 64 + lane;
    if (row1 >= OUT_F) row1 = 0;
    float w0[IN_F], w1[IN_F];
    const float4* W4 = (const float4*)W;
    #pragma unroll
    for (int j = 0; j < IN_F / 4; j++) {
        float4 t0 = W4[lane * (IN_F / 4) + j];
        w0[4*j+0] = t0.x; w0[4*j+1] = t0.y; w0[4*j+2] = t0.z; w0[4*j+3] = t0.w;
        float4 t1 = W4[row1 * (IN_F / 4) + j];
        w1[4*j+0] = t1.x; w1[4*j+1] = t1.y; w1[4*j+2] = t1.z; w1[4*j+3] = t1.w;
    }
    float bb0 = b[lane];
    float bb1 = b[row1];

    // coalesced preload of offs/deg for this wave's 16 nodes
    int o_l = 0, d_l = 0;
    if (lane < nmax) {
        o_l = offs[base + lane];
        d_l = deg[base + lane];
    }

    const float4* e4 = (const float4*)e;
    float* sr = &srow[w][0];

    // prefetch first chunk of node 0
    int id_next = 0;
    {
        int c0 = __shfl(d_l, 0, 64);
        int o0 = __shfl(o_l, 0, 64);
        int cc0 = (c0 < 64) ? c0 : 64;
        if (lane < cc0) id_next = eids[o0 + lane];
    }

    for (int j = 0; j < nmax; j++) {
        int id_cur = id_next;
        int o = __shfl(o_l, j, 64);
        int c = __shfl(d_l, j, 64);

        // prefetch node j+1's first id chunk (overlaps with this node's gather)
        if (j + 1 < nmax) {
            int cn = __shfl(d_l, j + 1, 64);
            int on = __shfl(o_l, j + 1, 64);
            int ccn = (cn < 64) ? cn : 64;
            if (lane < ccn) id_next = eids[on + lane];
        }

        float h0 = 0.0f, h1 = 0.0f;
        if (c > 0) {
            float4 a0 = {0,0,0,0}, a1 = {0,0,0,0}, a2 = {0,0,0,0}, a3 = {0,0,0,0};
            for (int cb = 0; cb < c; cb += 64) {
                int cc = c - cb; if (cc > 64) cc = 64;
                int ids = id_cur;
                if (cb > 0) ids = (lane < cc) ? eids[o + cb + lane] : 0;
                int ng = (cc + 3) >> 2;          // edge groups of 4
                int c1 = cc - 1;
                for (int i = 0; i < ng; i += 4) {
                    // 4 independent 1KB loads (4 edges each), branchless tail
                    int idx0 = (i + 0) * 4 + g;
                    int idx1 = (i + 1) * 4 + g;
                    int idx2 = (i + 2) * 4 + g;
                    int idx3 = (i + 3) * 4 + g;
                    int e0 = __shfl(ids, (idx0 < c1) ? idx0 : c1, 64);
                    int e1 = __shfl(ids, (idx1 < c1) ? idx1 : c1, 64);
                    int e2 = __shfl(ids, (idx2 < c1) ? idx2 : c1, 64);
                    int e3 = __shfl(ids, (idx3 < c1) ? idx3 : c1, 64);
                    float4 v0 = e4[(size_t)e0 * 16 + sub];
                    float4 v1 = e4[(size_t)e1 * 16 + sub];
                    float4 v2 = e4[(size_t)e2 * 16 + sub];
                    float4 v3 = e4[(size_t)e3 * 16 + sub];
                    float m0 = (idx0 < cc) ? 1.0f : 0.0f;
                    float m1 = (idx1 < cc) ? 1.0f : 0.0f;
                    float m2 = (idx2 < cc) ? 1.0f : 0.0f;
                    float m3 = (idx3 < cc) ? 1.0f : 0.0f;
                    a0.x = fmaf(v0.x, m0, a0.x); a0.y = fmaf(v0.y, m0, a0.y);
                    a0.z = fmaf(v0.z, m0, a0.z); a0.w = fmaf(v0.w, m0, a0.w);
                    a1.x = fmaf(v1.x, m1, a1.x); a1.y = fmaf(v1.y, m1, a1.y);
                    a1.z = fmaf(v1.z, m1, a1.z); a1.w = fmaf(v1.w, m1, a1.w);
                    a2.x = fmaf(v2.x, m2, a2.x); a2.y = fmaf(v2.y, m2, a2.y);
                    a2.z = fmaf(v2.z, m2, a2.z); a2.w = fmaf(v2.w, m2, a2.w);
                    a3.x = fmaf(v3.x, m3, a3.x); a3.y = fmaf(v3.y, m3, a3.y);
                    a3.z = fmaf(v3.z, m3, a3.z); a3.w = fmaf(v3.w, m3, a3.w);
                }
            }
            float4 s;
            s.x = (a0.x + a1.x) + (a2.x + a3.x);
            s.y = (a0.y + a1.y) + (a2.y + a3.y);
            s.z = (a0.z + a1.z) + (a2.z + a3.z);
            s.w = (a0.w + a1.w) + (a2.w + a3.w);
            // reduce across the 4 lane-groups
            s.x += __shfl_xor(s.x, 16, 64);
            s.y += __shfl_xor(s.y, 16, 64);
            s.z += __shfl_xor(s.z, 16, 64);
            s.w += __shfl_xor(s.w, 16, 64);
            s.x += __shfl_xor(s.x, 32, 64);
            s.y += __shfl_xor(s.y, 32, 64);
            s.z += __shfl_xor(s.z, 32, 64);
            s.w += __shfl_xor(s.w, 32, 64);
            float inv = 1.0f / (float)c;
            s.x *= inv; s.y *= inv; s.z *= inv; s.w *= inv;
            if (g == 0) ((float4*)sr)[sub] = s;

            // GEMV: 16 independent b128 broadcast reads from LDS (same wave)
            float aa0 = 0.f, aa1 = 0.f;
            const float4* sr4 = (const float4*)sr;
            #pragma unroll
            for (int q = 0; q < 16; q++) {
                float4 f = sr4[q];
                aa0 = fmaf(f.x, w0[4*q+0], aa0);  aa1 = fmaf(f.x, w1[4*q+0], aa1);
                aa0 = fmaf(f.y, w0[4*q+1], aa0);  aa1 = fmaf(f.y, w1[4*q+1], aa1);
                aa0 = fmaf(f.z, w0[4*q+2], aa0);  aa1 = fmaf(f.z, w1[4*q+2], aa1);
                aa0 = fmaf(f.w, w0[4*q+3], aa0);  aa1 = fmaf(f.w, w1[4*q+3], aa1);
            }
            h0 = aa0 + bb0;
            h1 = aa1 + bb1;
        }

        int node = base + j;
        size_t ob2 = (size_t)node * OUT_F;
        out[ob2 + lane] = h0;
        if (lane < OUT_F - 64) out[ob2 + 64 + lane] = h1;
    }
}

extern "C" void kernel_launch(void* const* d_in, const int* in_sizes, int n_in,
                              void* d_out, int out_size, void* d_ws, size_t ws_size,
                              hipStream_t stream) {
    const float* e   = (const float*)d_in[0];
    const int*   dst = (const int*)d_in[1];
    const float* W   = (const float*)d_in[2];
    const float* b   = (const float*)d_in[3];
    float* out = (float*)d_out;
    char* ws = (char*)d_ws;

    int* deg    = (int*)(ws + WS_DEG);
    int* offs   = (int*)(ws + WS_OFFS);
    int* cursor = (int*)(ws + WS_CUR);
    int* gcur   = (int*)(ws + WS_GCUR);
    int* eids   = (int*)(ws + WS_EIDS);

    hipMemsetAsync(deg, 0, N_NODES * sizeof(int), stream);
    hipMemsetAsync(gcur, 0, sizeof(int), stream);

    k_hist<<<(N_EDGES / 4 + 255) / 256, 256, 0, stream>>>(dst, deg);
    k_scan<<<(N_NODES + 255) / 256, 256, 0, stream>>>(deg, offs, cursor, gcur);
    k_scat<<<(N_EDGES / 4 + 255) / 256, 256, 0, stream>>>(dst, cursor, eids);

    // 6250 waves x 16 nodes; 4 waves per block -> 1563 blocks
    int nwaves = (N_NODES + NPW - 1) / NPW;
    int nblocks = (nwaves + 3) / 4;
    k_gather<<<nblocks, 256, 0, stream>>>(e, eids, offs, deg, W, b, out);
}

// Round 3
// 655.412 us; speedup vs baseline: 1.2841x; 1.2598x over previous
//
#include <hip/hip_runtime.h>

#define N_NODES 100000
#define N_EDGES 1600000
#define IN_F    64
#define OUT_F   100

// ==================== bucket-path constants (proven R0 front-end) ====================
#define K_BUCKETS 1563            // bucket = dst >> 6  (64 nodes per bucket)
#define NBLK      500             // edge-pass blocks
#define EPB       3200            // edges per block (exact: 500*3200 = 1.6M)
#define SCAN_LEN  (K_BUCKETS * NBLK)            // 781500
#define SCH       2048            // elements per scan block
#define SB        ((SCAN_LEN + SCH - 1) / SCH)  // 382
#define CAP       3072            // LDS sorted-list capacity (avg 1024, +64 sigma)

// ---- main-path workspace layout (bytes) ----
#define OFF_CNT   0                         // int[SCAN_LEN]  (3.126 MB)
#define OFF_PART  (SCAN_LEN * 4)            // int[SB]
#define OFF_BIN   (SCAN_LEN * 4 + 2048)     // int[N_EDGES]   (6.4 MB)
#define OFF_MSUM  (((OFF_BIN + N_EDGES * 4) + 255) & ~255)   // float[N_NODES][64] (25.6 MB)
#define OFF_DEGO  (OFF_MSUM + N_NODES * IN_F * 4)            // int[N_NODES]
#define WS_NEEDED ((size_t)OFF_DEGO + (size_t)N_NODES * 4)   // ~35.5 MB

// ---- fallback layout (atomic path, < 8 MB) ----
#define FB_DEG     0
#define FB_OFFS    524288
#define FB_CURSOR  1048576
#define FB_GCUR    1572864
#define FB_EIDS    1573888

// ===================== pass A: per-block bucket histogram =====================
__global__ void __launch_bounds__(256) k_count(const int* __restrict__ dst,
                                               int* __restrict__ cnt) {
    __shared__ int h[K_BUCKETS];
    for (int i = threadIdx.x; i < K_BUCKETS; i += 256) h[i] = 0;
    __syncthreads();
    int base = blockIdx.x * EPB;
    #pragma unroll
    for (int it = 0; it < 3; it++) {
        int i = base + it * 1024 + threadIdx.x * 4;
        int4 d = *(const int4*)(dst + i);
        atomicAdd(&h[d.x >> 6], 1);
        atomicAdd(&h[d.y >> 6], 1);
        atomicAdd(&h[d.z >> 6], 1);
        atomicAdd(&h[d.w >> 6], 1);
    }
    if (threadIdx.x < 128) {
        int i = base + 3072 + threadIdx.x;
        atomicAdd(&h[dst[i] >> 6], 1);
    }
    __syncthreads();
    for (int k = threadIdx.x; k < K_BUCKETS; k += 256)
        cnt[k * NBLK + blockIdx.x] = h[k];
}

// ===================== pass B: flat exclusive scan of cnt =====================
__global__ void k_s1(const int* __restrict__ cnt, int* __restrict__ part) {
    __shared__ int ws_[4];
    int b0 = blockIdx.x * SCH;
    int t = threadIdx.x;
    int tot = 0;
    #pragma unroll
    for (int i = 0; i < 8; i++) {
        int idx = b0 + i * 256 + t;
        if (idx < SCAN_LEN) tot += cnt[idx];
    }
    #pragma unroll
    for (int off = 32; off; off >>= 1) tot += __shfl_down(tot, off, 64);
    if ((t & 63) == 0) ws_[t >> 6] = tot;
    __syncthreads();
    if (t == 0) part[blockIdx.x] = ws_[0] + ws_[1] + ws_[2] + ws_[3];
}

__global__ void k_s2(int* __restrict__ part) {
    int lane = threadIdx.x;
    int carry = 0;
    for (int b0 = 0; b0 < SB; b0 += 64) {
        int idx = b0 + lane;
        int v = (idx < SB) ? part[idx] : 0;
        int x = v;
        #pragma unroll
        for (int off = 1; off < 64; off <<= 1) {
            int y = __shfl_up(x, off, 64);
            if (lane >= off) x += y;
        }
        int tot = __shfl(x, 63, 64);
        if (idx < SB) part[idx] = carry + x - v;
        carry += tot;
    }
}

__global__ void k_s3(int* __restrict__ cnt, const int* __restrict__ part) {
    __shared__ int wsum[4];
    int t = threadIdx.x, lane = t & 63, w = t >> 6;
    int idx0 = blockIdx.x * SCH + t * 8;
    int v[8];
    int s = 0;
    #pragma unroll
    for (int i = 0; i < 8; i++) {
        v[i] = (idx0 + i < SCAN_LEN) ? cnt[idx0 + i] : 0;
        s += v[i];
    }
    int x = s;
    #pragma unroll
    for (int off = 1; off < 64; off <<= 1) {
        int y = __shfl_up(x, off, 64);
        if (lane >= off) x += y;
    }
    if (lane == 63) wsum[w] = x;
    __syncthreads();
    int wb = 0;
    for (int i = 0; i < w; i++) wb += wsum[i];
    int run = part[blockIdx.x] + wb + (x - s);
    #pragma unroll
    for (int i = 0; i < 8; i++) {
        int tmp = v[i];
        if (idx0 + i < SCAN_LEN) cnt[idx0 + i] = run;
        run += tmp;
    }
}

// ===================== pass C: bin edges (LDS cursors only) =====================
__global__ void __launch_bounds__(256) k_bin(const int* __restrict__ dst,
                                             const int* __restrict__ scn,
                                             int* __restrict__ binned) {
    __shared__ int cur[K_BUCKETS];
    for (int k = threadIdx.x; k < K_BUCKETS; k += 256)
        cur[k] = scn[k * NBLK + blockIdx.x];
    __syncthreads();
    int base = blockIdx.x * EPB;
    #pragma unroll
    for (int it = 0; it < 3; it++) {
        int i = base + it * 1024 + threadIdx.x * 4;
        int4 d = *(const int4*)(dst + i);
        int p;
        p = atomicAdd(&cur[d.x >> 6], 1); binned[p] = ((d.x & 63) << 21) | i;
        p = atomicAdd(&cur[d.y >> 6], 1); binned[p] = ((d.y & 63) << 21) | (i + 1);
        p = atomicAdd(&cur[d.z >> 6], 1); binned[p] = ((d.z & 63) << 21) | (i + 2);
        p = atomicAdd(&cur[d.w >> 6], 1); binned[p] = ((d.w & 63) << 21) | (i + 3);
    }
    if (threadIdx.x < 128) {
        int i = base + 3072 + threadIdx.x;
        int d = dst[i];
        int p = atomicAdd(&cur[d >> 6], 1);
        binned[p] = ((d & 63) << 21) | i;
    }
}

// ===================== gather + mean ONLY (high occupancy, no W regs) =====================
// One block per bucket (64 nodes). Counting-sort bucket's edges by local node
// id in LDS (unchanged from proven k_fused). Gather uses the float4-lane
// layout (g=lane>>4, sub=lane&15): one wave-load covers FOUR edge rows (1KB),
// 4 independent loads in flight, branchless masked-FMA tail, 8-shfl reduce.
// GEMV removed -> ~90 VGPR -> 4 blocks/CU (2x MLP vs fused version).
// Writes msum[node][64] (256B coalesced) + degOut[node].
__global__ void __launch_bounds__(256, 4) k_gsum(
        const float* __restrict__ e, const int* __restrict__ binned,
        const int* __restrict__ scn, float* __restrict__ msum,
        int* __restrict__ degOut) {
    __shared__ int deg[64];
    __shared__ int lofs[64];
    __shared__ int sorted[CAP];

    int tid = threadIdx.x, lane = tid & 63, w = tid >> 6;
    int sub = lane & 15, g = lane >> 4;
    int bk = blockIdx.x;
    int base = scn[bk * NBLK];
    int end  = (bk + 1 < K_BUCKETS) ? scn[(bk + 1) * NBLK] : N_EDGES;
    int cntb = end - base;

    for (int i = tid; i < 64; i += 256) deg[i] = 0;
    __syncthreads();

    bool fast = (cntb <= CAP);
    if (fast) {
        int pk[12], rk[12];
        int nI = (cntb + 255) >> 8;
        #pragma unroll
        for (int i = 0; i < 12; i++) {           // static unroll: keep pk/rk in regs
            pk[i] = -1; rk[i] = 0;
            if (i < nI) {
                int idx = tid + i * 256;
                if (idx < cntb) {
                    int p = binned[base + idx];
                    pk[i] = p;
                    rk[i] = atomicAdd(&deg[p >> 21], 1);
                }
            }
        }
        __syncthreads();
        if (w == 0) {
            int d = deg[lane];
            int x = d;
            #pragma unroll
            for (int off = 1; off < 64; off <<= 1) {
                int y = __shfl_up(x, off, 64);
                if (lane >= off) x += y;
            }
            lofs[lane] = x - d;
        }
        __syncthreads();
        #pragma unroll
        for (int i = 0; i < 12; i++) {
            if (pk[i] >= 0) {
                int lid = pk[i] >> 21;
                sorted[lofs[lid] + rk[i]] = pk[i] & 0x1FFFFF;
            }
        }
        __syncthreads();
        // coalesced bulk degree write
        if (w == 0) {
            int node = bk * 64 + lane;
            if (node < N_NODES) degOut[node] = deg[lane];
        }
    }

    const float4* e4 = (const float4*)e;
    float4* msum4 = (float4*)msum;

    for (int t = 0; t < 16; t++) {
        int lid = w * 16 + t;
        int node = bk * 64 + lid;
        if (node >= N_NODES) break;          // only last (32-node) bucket

        if (fast) {
            int o = lofs[lid];
            int c = deg[lid];
            if (c > 0) {
                float4 a0 = {0,0,0,0}, a1 = {0,0,0,0}, a2 = {0,0,0,0}, a3 = {0,0,0,0};
                for (int cb = 0; cb < c; cb += 64) {
                    int cc = c - cb; if (cc > 64) cc = 64;
                    int ng = (cc + 3) >> 2;          // edge groups of 4
                    int ob = o + cb;
                    for (int i = 0; i < ng; i += 4) {
                        // 4 independent 1KB loads (4 edges each), branchless
                        int idx0 = (i + 0) * 4 + g;
                        int idx1 = (i + 1) * 4 + g;
                        int idx2 = (i + 2) * 4 + g;
                        int idx3 = (i + 3) * 4 + g;
                        int c1 = cc - 1;
                        int e0 = sorted[ob + ((idx0 < c1) ? idx0 : c1)];
                        int e1 = sorted[ob + ((idx1 < c1) ? idx1 : c1)];
                        int e2 = sorted[ob + ((idx2 < c1) ? idx2 : c1)];
                        int e3 = sorted[ob + ((idx3 < c1) ? idx3 : c1)];
                        float4 v0 = e4[(size_t)e0 * 16 + sub];
                        float4 v1 = e4[(size_t)e1 * 16 + sub];
                        float4 v2 = e4[(size_t)e2 * 16 + sub];
                        float4 v3 = e4[(size_t)e3 * 16 + sub];
                        float m0 = (idx0 < cc) ? 1.0f : 0.0f;
                        float m1 = (idx1 < cc) ? 1.0f : 0.0f;
                        float m2 = (idx2 < cc) ? 1.0f : 0.0f;
                        float m3 = (idx3 < cc) ? 1.0f : 0.0f;
                        a0.x = fmaf(v0.x, m0, a0.x); a0.y = fmaf(v0.y, m0, a0.y);
                        a0.z = fmaf(v0.z, m0, a0.z); a0.w = fmaf(v0.w, m0, a0.w);
                        a1.x = fmaf(v1.x, m1, a1.x); a1.y = fmaf(v1.y, m1, a1.y);
                        a1.z = fmaf(v1.z, m1, a1.z); a1.w = fmaf(v1.w, m1, a1.w);
                        a2.x = fmaf(v2.x, m2, a2.x); a2.y = fmaf(v2.y, m2, a2.y);
                        a2.z = fmaf(v2.z, m2, a2.z); a2.w = fmaf(v2.w, m2, a2.w);
                        a3.x = fmaf(v3.x, m3, a3.x); a3.y = fmaf(v3.y, m3, a3.y);
                        a3.z = fmaf(v3.z, m3, a3.z); a3.w = fmaf(v3.w, m3, a3.w);
                    }
                }
                float4 s;
                s.x = (a0.x + a1.x) + (a2.x + a3.x);
                s.y = (a0.y + a1.y) + (a2.y + a3.y);
                s.z = (a0.z + a1.z) + (a2.z + a3.z);
                s.w = (a0.w + a1.w) + (a2.w + a3.w);
                // reduce across the 4 lane-groups
                s.x += __shfl_xor(s.x, 16, 64);
                s.y += __shfl_xor(s.y, 16, 64);
                s.z += __shfl_xor(s.z, 16, 64);
                s.w += __shfl_xor(s.w, 16, 64);
                s.x += __shfl_xor(s.x, 32, 64);
                s.y += __shfl_xor(s.y, 32, 64);
                s.z += __shfl_xor(s.z, 32, 64);
                s.w += __shfl_xor(s.w, 32, 64);
                float inv = 1.0f / (float)c;
                s.x *= inv; s.y *= inv; s.z *= inv; s.w *= inv;
                if (g == 0) msum4[(size_t)node * 16 + sub] = s;   // 256B coalesced
            }
        } else {
            // correctness-only path for pathological bucket overflow
            int c = 0;
            float s0 = 0.f;
            for (int j0 = 0; j0 < cntb; j0 += 64) {
                int idx = j0 + lane;
                int p = (idx < cntb) ? binned[base + idx] : -1;
                bool m = (p >= 0) && ((p >> 21) == lid);
                unsigned long long msk = __ballot(m);
                c += __popcll(msk);
                while (msk) {
                    int l = __ffsll((long long)msk) - 1;
                    msk &= msk - 1;
                    int eid = __builtin_amdgcn_readlane(p, l) & 0x1FFFFF;
                    s0 += e[((size_t)eid << 6) + lane];
                }
            }
            if (c > 0) msum[(size_t)node * 64 + lane] = s0 * (1.0f / (float)c);
            if (lane == 0) degOut[node] = c;
        }
    }
}

// ===================== GEMV: msum @ W^T + b (zero for deg==0) =====================
// One wave per 16 consecutive nodes. Stage the wave's 16 mean rows with one
// coalesced 4KB LDS copy, then GEMV against W held in 128 VGPRs via 16 b128
// LDS broadcast reads per node. Streaming: 25.6MB in + 40MB out.
__global__ void __launch_bounds__(256, 2) k_gemv(
        const float* __restrict__ msum, const int* __restrict__ degOut,
        const float* __restrict__ W, const float* __restrict__ b,
        float* __restrict__ out) {
    __shared__ __align__(16) float srow[4][16 * 64];
    int lane = threadIdx.x & 63, w = threadIdx.x >> 6;
    int wave = blockIdx.x * 4 + w;
    int base = wave * 16;
    if (base >= N_NODES) return;               // no barriers below: safe
    int nmax = N_NODES - base;
    if (nmax > 16) nmax = 16;

    // W rows into registers (lane -> rows lane and 64+lane)
    int row1 = 64 + lane;
    if (row1 >= OUT_F) row1 = 0;
    float w0[IN_F], w1[IN_F];
    const float4* W4 = (const float4*)W;
    #pragma unroll
    for (int j = 0; j < IN_F / 4; j++) {
        float4 t0 = W4[lane * (IN_F / 4) + j];
        w0[4*j+0] = t0.x; w0[4*j+1] = t0.y; w0[4*j+2] = t0.z; w0[4*j+3] = t0.w;
        float4 t1 = W4[row1 * (IN_F / 4) + j];
        w1[4*j+0] = t1.x; w1[4*j+1] = t1.y; w1[4*j+2] = t1.z; w1[4*j+3] = t1.w;
    }
    float bb0 = b[lane];
    float bb1 = b[row1];

    // coalesced degree preload for the wave's 16 nodes
    int d_l = 0;
    if (lane < nmax) d_l = degOut[base + lane];

    // stage 16 mean rows: up to 4KB contiguous, coalesced
    float4* s4 = (float4*)&srow[w][0];
    const float4* m4 = (const float4*)msum + (size_t)base * 16;
    int nf4 = nmax * 16;
    #pragma unroll
    for (int it = 0; it < 4; it++) {
        int idx = it * 64 + lane;
        if (idx < nf4) s4[idx] = m4[idx];
    }
    // (within-wave LDS write->read: compiler inserts the lgkmcnt wait)

    for (int j = 0; j < nmax; j++) {
        int c = __shfl(d_l, j, 64);
        float h0 = 0.0f, h1 = 0.0f;
        if (c > 0) {
            float aa0 = 0.f, aa1 = 0.f;
            const float4* sr4 = (const float4*)&srow[w][j * 64];
            #pragma unroll
            for (int q = 0; q < 16; q++) {
                float4 f = sr4[q];
                aa0 = fmaf(f.x, w0[4*q+0], aa0);  aa1 = fmaf(f.x, w1[4*q+0], aa1);
                aa0 = fmaf(f.y, w0[4*q+1], aa0);  aa1 = fmaf(f.y, w1[4*q+1], aa1);
                aa0 = fmaf(f.z, w0[4*q+2], aa0);  aa1 = fmaf(f.z, w1[4*q+2], aa1);
                aa0 = fmaf(f.w, w0[4*q+3], aa0);  aa1 = fmaf(f.w, w1[4*q+3], aa1);
            }
            h0 = aa0 + bb0;
            h1 = aa1 + bb1;
        }
        int node = base + j;
        size_t ob2 = (size_t)node * OUT_F;
        out[ob2 + lane] = h0;
        if (lane < OUT_F - 64) out[ob2 + 64 + lane] = h1;
    }
}

// ===================== fallback path (atomic-based, < 35.5 MB ws) =====================
__global__ void fb_hist(const int* __restrict__ dst, int* __restrict__ deg) {
    int i = (blockIdx.x * blockDim.x + threadIdx.x) * 4;
    if (i + 3 < N_EDGES) {
        int4 d = *(const int4*)(dst + i);
        atomicAdd(&deg[d.x], 1); atomicAdd(&deg[d.y], 1);
        atomicAdd(&deg[d.z], 1); atomicAdd(&deg[d.w], 1);
    } else {
        for (int k = i; k < N_EDGES; k++) atomicAdd(&deg[dst[k]], 1);
    }
}

__global__ void fb_scan(const int* __restrict__ deg, int* __restrict__ offs,
                        int* __restrict__ cursor, int* __restrict__ gcur) {
    int n = blockIdx.x * blockDim.x + threadIdx.x;
    int lane = threadIdx.x & 63;
    int d = (n < N_NODES) ? deg[n] : 0;
    int x = d;
    #pragma unroll
    for (int off = 1; off < 64; off <<= 1) {
        int y = __shfl_up(x, off, 64);
        if (lane >= off) x += y;
    }
    int excl = x - d;
    int total = __shfl(x, 63, 64);
    int bs = 0;
    if (lane == 63) bs = atomicAdd(gcur, total);
    bs = __shfl(bs, 63, 64);
    if (n < N_NODES) {
        offs[n] = bs + excl;
        cursor[n] = bs + excl;
    }
}

__global__ void fb_scatter(const int* __restrict__ dst, int* __restrict__ cursor,
                           int* __restrict__ eids) {
    int i = (blockIdx.x * blockDim.x + threadIdx.x) * 4;
    if (i + 3 < N_EDGES) {
        int4 d = *(const int4*)(dst + i);
        int p0 = atomicAdd(&cursor[d.x], 1);
        int p1 = atomicAdd(&cursor[d.y], 1);
        int p2 = atomicAdd(&cursor[d.z], 1);
        int p3 = atomicAdd(&cursor[d.w], 1);
        eids[p0] = i; eids[p1] = i + 1; eids[p2] = i + 2; eids[p3] = i + 3;
    } else {
        for (int k = i; k < N_EDGES; k++) {
            int pos = atomicAdd(&cursor[dst[k]], 1);
            eids[pos] = k;
        }
    }
}

__global__ void __launch_bounds__(256) fb_gather(
        const float* __restrict__ e, const int* __restrict__ eids,
        const int* __restrict__ offs, const int* __restrict__ deg,
        const float* __restrict__ W, const float* __restrict__ b,
        float* __restrict__ out, int n_waves_total) {
    __shared__ float srow[4][64];
    int lane = threadIdx.x & 63, w = (threadIdx.x >> 6) & 3;
    int wid  = (blockIdx.x * blockDim.x + threadIdx.x) >> 6;
    int row1 = 64 + lane;
    if (row1 >= OUT_F) row1 = 0;
    float w0[IN_F], w1[IN_F];
    const float4* W4 = (const float4*)W;
    #pragma unroll
    for (int j = 0; j < IN_F / 4; j++) {
        float4 t0 = W4[lane * (IN_F / 4) + j];
        w0[4*j+0] = t0.x; w0[4*j+1] = t0.y; w0[4*j+2] = t0.z; w0[4*j+3] = t0.w;
        float4 t1 = W4[row1 * (IN_F / 4) + j];
        w1[4*j+0] = t1.x; w1[4*j+1] = t1.y; w1[4*j+2] = t1.z; w1[4*j+3] = t1.w;
    }
    float bb0 = b[lane];
    float bb1 = b[row1];
    for (int n = wid; n < N_NODES; n += n_waves_total) {
        int o = __builtin_amdgcn_readfirstlane(offs[n]);
        int c = __builtin_amdgcn_readfirstlane(deg[n]);
        float s0 = 0.f, s1 = 0.f;
        for (int cb = 0; cb < c; cb += 64) {
            int cc = c - cb; if (cc > 64) cc = 64;
            int myeid = 0;
            if (lane < cc) myeid = eids[o + cb + lane];
            for (int j = 0; j < cc; j += 2) {
                int i0 = __builtin_amdgcn_readlane(myeid, j);
                s0 += e[((size_t)i0 << 6) + lane];
                if (j + 1 < cc) {
                    int i1 = __builtin_amdgcn_readlane(myeid, j + 1);
                    s1 += e[((size_t)i1 << 6) + lane];
                }
            }
        }
        float* sr = &srow[w][0];
        sr[lane] = (s0 + s1) * ((c > 0) ? 1.0f / (float)c : 0.0f);
        float a0 = 0.f, a1 = 0.f;
        const float4* sr4 = (const float4*)sr;
        #pragma unroll
        for (int q = 0; q < 16; q++) {
            float4 f = sr4[q];
            a0 = fmaf(f.x, w0[4*q+0], a0);  a1 = fmaf(f.x, w1[4*q+0], a1);
            a0 = fmaf(f.y, w0[4*q+1], a0);  a1 = fmaf(f.y, w1[4*q+1], a1);
            a0 = fmaf(f.z, w0[4*q+2], a0);  a1 = fmaf(f.z, w1[4*q+2], a1);
            a0 = fmaf(f.w, w0[4*q+3], a0);  a1 = fmaf(f.w, w1[4*q+3], a1);
        }
        float h0 = (c > 0) ? a0 + bb0 : 0.0f;
        float h1 = (c > 0) ? a1 + bb1 : 0.0f;
        size_t ob = (size_t)n * OUT_F;
        out[ob + lane] = h0;
        if (lane < OUT_F - 64) out[ob + 64 + lane] = h1;
    }
}

extern "C" void kernel_launch(void* const* d_in, const int* in_sizes, int n_in,
                              void* d_out, int out_size, void* d_ws, size_t ws_size,
                              hipStream_t stream) {
    const float* e   = (const float*)d_in[0];
    const int*   dst = (const int*)d_in[1];
    const float* W   = (const float*)d_in[2];
    const float* b   = (const float*)d_in[3];
    float* out = (float*)d_out;
    char* ws = (char*)d_ws;

    if (ws_size >= WS_NEEDED) {
        int*   cnt    = (int*)(ws + OFF_CNT);
        int*   part   = (int*)(ws + OFF_PART);
        int*   binned = (int*)(ws + OFF_BIN);
        float* msum   = (float*)(ws + OFF_MSUM);
        int*   degOut = (int*)(ws + OFF_DEGO);

        k_count<<<NBLK, 256, 0, stream>>>(dst, cnt);
        k_s1   <<<SB, 256, 0, stream>>>(cnt, part);
        k_s2   <<<1, 64, 0, stream>>>(part);
        k_s3   <<<SB, 256, 0, stream>>>(cnt, part);
        k_bin  <<<NBLK, 256, 0, stream>>>(dst, cnt, binned);
        k_gsum <<<K_BUCKETS, 256, 0, stream>>>(e, binned, cnt, msum, degOut);
        // 6250 waves x 16 nodes, 4 waves/block
        k_gemv <<<(N_NODES / 16 + 3) / 4 + 1, 256, 0, stream>>>(msum, degOut, W, b, out);
    } else {
        int* deg    = (int*)(ws + FB_DEG);
        int* offs   = (int*)(ws + FB_OFFS);
        int* cursor = (int*)(ws + FB_CURSOR);
        int* gcur   = (int*)(ws + FB_GCUR);
        int* eids   = (int*)(ws + FB_EIDS);

        hipMemsetAsync(deg, 0, N_NODES * sizeof(int), stream);
        hipMemsetAsync(gcur, 0, sizeof(int), stream);
        fb_hist   <<<(N_EDGES / 4 + 255) / 256, 256, 0, stream>>>(dst, deg);
        fb_scan   <<<(N_NODES + 255) / 256, 256, 0, stream>>>(deg, offs, cursor, gcur);
        fb_scatter<<<(N_EDGES / 4 + 255) / 256, 256, 0, stream>>>(dst, cursor, eids);
        fb_gather <<<8192, 256, 0, stream>>>(e, eids, offs, deg, W, b, out, 8192 * 4);
    }
}

// Round 4
// 651.020 us; speedup vs baseline: 1.2928x; 1.0067x over previous
//
#include <hip/hip_runtime.h>

#define N_NODES 100000
#define N_EDGES 1600000
#define IN_F    64
#define OUT_F   100

// ==================== bucket-path constants (proven R0 front-end) ====================
#define K_BUCKETS 1563            // bucket = dst >> 6  (64 nodes per bucket)
#define NBLK      500             // edge-pass blocks
#define EPB       3200            // edges per block (exact: 500*3200 = 1.6M)
#define SCAN_LEN  (K_BUCKETS * NBLK)            // 781500
#define SCH       2048            // elements per scan block
#define SB        ((SCAN_LEN + SCH - 1) / SCH)  // 382
#define CAP       3072            // LDS sorted-list capacity (avg 1024, +64 sigma)

// ---- main-path workspace layout (bytes) ----
#define OFF_CNT   0                         // int[SCAN_LEN]  (3.126 MB)
#define OFF_PART  (SCAN_LEN * 4)            // int[SB]
#define OFF_BIN   (SCAN_LEN * 4 + 2048)     // int[N_EDGES]   (6.4 MB)
#define OFF_MSUM  (((OFF_BIN + N_EDGES * 4) + 255) & ~255)   // float[N_NODES][64] (25.6 MB)
#define OFF_DEGO  (OFF_MSUM + N_NODES * IN_F * 4)            // int[N_NODES]
#define WS_NEEDED ((size_t)OFF_DEGO + (size_t)N_NODES * 4)   // ~35.5 MB

// ---- fallback layout (atomic path, < 8 MB) ----
#define FB_DEG     0
#define FB_OFFS    524288
#define FB_CURSOR  1048576
#define FB_GCUR    1572864
#define FB_EIDS    1573888

// ===================== pass A: per-block bucket histogram =====================
__global__ void __launch_bounds__(256) k_count(const int* __restrict__ dst,
                                               int* __restrict__ cnt) {
    __shared__ int h[K_BUCKETS];
    for (int i = threadIdx.x; i < K_BUCKETS; i += 256) h[i] = 0;
    __syncthreads();
    int base = blockIdx.x * EPB;
    #pragma unroll
    for (int it = 0; it < 3; it++) {
        int i = base + it * 1024 + threadIdx.x * 4;
        int4 d = *(const int4*)(dst + i);
        atomicAdd(&h[d.x >> 6], 1);
        atomicAdd(&h[d.y >> 6], 1);
        atomicAdd(&h[d.z >> 6], 1);
        atomicAdd(&h[d.w >> 6], 1);
    }
    if (threadIdx.x < 128) {
        int i = base + 3072 + threadIdx.x;
        atomicAdd(&h[dst[i] >> 6], 1);
    }
    __syncthreads();
    for (int k = threadIdx.x; k < K_BUCKETS; k += 256)
        cnt[k * NBLK + blockIdx.x] = h[k];
}

// ===================== pass B: flat exclusive scan of cnt =====================
__global__ void k_s1(const int* __restrict__ cnt, int* __restrict__ part) {
    __shared__ int ws_[4];
    int b0 = blockIdx.x * SCH;
    int t = threadIdx.x;
    int tot = 0;
    #pragma unroll
    for (int i = 0; i < 8; i++) {
        int idx = b0 + i * 256 + t;
        if (idx < SCAN_LEN) tot += cnt[idx];
    }
    #pragma unroll
    for (int off = 32; off; off >>= 1) tot += __shfl_down(tot, off, 64);
    if ((t & 63) == 0) ws_[t >> 6] = tot;
    __syncthreads();
    if (t == 0) part[blockIdx.x] = ws_[0] + ws_[1] + ws_[2] + ws_[3];
}

__global__ void k_s2(int* __restrict__ part) {
    int lane = threadIdx.x;
    int carry = 0;
    for (int b0 = 0; b0 < SB; b0 += 64) {
        int idx = b0 + lane;
        int v = (idx < SB) ? part[idx] : 0;
        int x = v;
        #pragma unroll
        for (int off = 1; off < 64; off <<= 1) {
            int y = __shfl_up(x, off, 64);
            if (lane >= off) x += y;
        }
        int tot = __shfl(x, 63, 64);
        if (idx < SB) part[idx] = carry + x - v;
        carry += tot;
    }
}

__global__ void k_s3(int* __restrict__ cnt, const int* __restrict__ part) {
    __shared__ int wsum[4];
    int t = threadIdx.x, lane = t & 63, w = t >> 6;
    int idx0 = blockIdx.x * SCH + t * 8;
    int v[8];
    int s = 0;
    #pragma unroll
    for (int i = 0; i < 8; i++) {
        v[i] = (idx0 + i < SCAN_LEN) ? cnt[idx0 + i] : 0;
        s += v[i];
    }
    int x = s;
    #pragma unroll
    for (int off = 1; off < 64; off <<= 1) {
        int y = __shfl_up(x, off, 64);
        if (lane >= off) x += y;
    }
    if (lane == 63) wsum[w] = x;
    __syncthreads();
    int wb = 0;
    for (int i = 0; i < w; i++) wb += wsum[i];
    int run = part[blockIdx.x] + wb + (x - s);
    #pragma unroll
    for (int i = 0; i < 8; i++) {
        int tmp = v[i];
        if (idx0 + i < SCAN_LEN) cnt[idx0 + i] = run;
        run += tmp;
    }
}

// ===================== pass C: bin edges (LDS cursors only) =====================
__global__ void __launch_bounds__(256) k_bin(const int* __restrict__ dst,
                                             const int* __restrict__ scn,
                                             int* __restrict__ binned) {
    __shared__ int cur[K_BUCKETS];
    for (int k = threadIdx.x; k < K_BUCKETS; k += 256)
        cur[k] = scn[k * NBLK + blockIdx.x];
    __syncthreads();
    int base = blockIdx.x * EPB;
    #pragma unroll
    for (int it = 0; it < 3; it++) {
        int i = base + it * 1024 + threadIdx.x * 4;
        int4 d = *(const int4*)(dst + i);
        int p;
        p = atomicAdd(&cur[d.x >> 6], 1); binned[p] = ((d.x & 63) << 21) | i;
        p = atomicAdd(&cur[d.y >> 6], 1); binned[p] = ((d.y & 63) << 21) | (i + 1);
        p = atomicAdd(&cur[d.z >> 6], 1); binned[p] = ((d.z & 63) << 21) | (i + 2);
        p = atomicAdd(&cur[d.w >> 6], 1); binned[p] = ((d.w & 63) << 21) | (i + 3);
    }
    if (threadIdx.x < 128) {
        int i = base + 3072 + threadIdx.x;
        int d = dst[i];
        int p = atomicAdd(&cur[d >> 6], 1);
        binned[p] = ((d & 63) << 21) | i;
    }
}

// ===================== gather + mean: ONE NODE PER 16-LANE GROUP =====================
// One block per bucket (64 nodes). Counting-sort bucket's edges by local node
// id in LDS (unchanged, proven). Gather phase: each 16-lane group owns ONE
// node and holds its full 64-float row (float4 per lane). It accumulates its
// node's edges locally -> NO cross-lane reduce at all, no per-node sync; 4
// independent load streams per wave (4 groups x 4 unclamped loads in flight).
// Per wave step, the 4 groups write 4 consecutive nodes' mean rows = 1KB
// contiguous store. Same fp32 FMA accumulation tree as verified version.
__global__ void __launch_bounds__(256, 4) k_gsum(
        const float* __restrict__ e, const int* __restrict__ binned,
        const int* __restrict__ scn, float* __restrict__ msum,
        int* __restrict__ degOut) {
    __shared__ int deg[64];
    __shared__ int lofs[64];
    __shared__ int sorted[CAP];

    int tid = threadIdx.x, lane = tid & 63, w = tid >> 6;
    int sub = lane & 15, g = lane >> 4;
    int bk = blockIdx.x;
    int base = scn[bk * NBLK];
    int end  = (bk + 1 < K_BUCKETS) ? scn[(bk + 1) * NBLK] : N_EDGES;
    int cntb = end - base;

    for (int i = tid; i < 64; i += 256) deg[i] = 0;
    __syncthreads();

    bool fast = (cntb <= CAP);
    if (fast) {
        int pk[12], rk[12];
        int nI = (cntb + 255) >> 8;
        #pragma unroll
        for (int i = 0; i < 12; i++) {
            pk[i] = -1; rk[i] = 0;
            if (i < nI) {
                int idx = tid + i * 256;
                if (idx < cntb) {
                    int p = binned[base + idx];
                    pk[i] = p;
                    rk[i] = atomicAdd(&deg[p >> 21], 1);
                }
            }
        }
        __syncthreads();
        if (w == 0) {
            int d = deg[lane];
            int x = d;
            #pragma unroll
            for (int off = 1; off < 64; off <<= 1) {
                int y = __shfl_up(x, off, 64);
                if (lane >= off) x += y;
            }
            lofs[lane] = x - d;
        }
        __syncthreads();
        #pragma unroll
        for (int i = 0; i < 12; i++) {
            if (pk[i] >= 0) {
                int lid = pk[i] >> 21;
                sorted[lofs[lid] + rk[i]] = pk[i] & 0x1FFFFF;
            }
        }
        __syncthreads();
        if (w == 0) {
            int node = bk * 64 + lane;
            if (node < N_NODES) degOut[node] = deg[lane];
        }
    }

    const float4* e4 = (const float4*)e;
    float4* msum4 = (float4*)msum;

    if (fast) {
        #pragma unroll
        for (int t = 0; t < 4; t++) {
            int lid = w * 16 + t * 4 + g;      // this group's node
            int node = bk * 64 + lid;
            bool valid = (node < N_NODES);     // only last (32-node) bucket clips
            int o = valid ? lofs[lid] : 0;
            int c = valid ? deg[lid] : 0;
            float4 accA = {0,0,0,0}, accB = {0,0,0,0};
            int cm1 = c - 1;
            for (int k = 0; k < c; k += 4) {
                // 4 edge ids for this group (broadcast LDS reads; clamped tail)
                int e0 = sorted[o + k];
                int e1 = sorted[o + ((k + 1 < cm1) ? k + 1 : cm1)];
                int e2 = sorted[o + ((k + 2 < cm1) ? k + 2 : cm1)];
                int e3 = sorted[o + ((k + 3 < cm1) ? k + 3 : cm1)];
                // 4 independent 256B row loads (16 lanes x float4 each)
                float4 v0 = e4[(size_t)e0 * 16 + sub];
                float4 v1 = e4[(size_t)e1 * 16 + sub];
                float4 v2 = e4[(size_t)e2 * 16 + sub];
                float4 v3 = e4[(size_t)e3 * 16 + sub];
                float m1 = (k + 1 < c) ? 1.0f : 0.0f;
                float m2 = (k + 2 < c) ? 1.0f : 0.0f;
                float m3 = (k + 3 < c) ? 1.0f : 0.0f;
                accA.x += v0.x; accA.y += v0.y; accA.z += v0.z; accA.w += v0.w;
                accB.x = fmaf(v1.x, m1, accB.x); accB.y = fmaf(v1.y, m1, accB.y);
                accB.z = fmaf(v1.z, m1, accB.z); accB.w = fmaf(v1.w, m1, accB.w);
                accA.x = fmaf(v2.x, m2, accA.x); accA.y = fmaf(v2.y, m2, accA.y);
                accA.z = fmaf(v2.z, m2, accA.z); accA.w = fmaf(v2.w, m2, accA.w);
                accB.x = fmaf(v3.x, m3, accB.x); accB.y = fmaf(v3.y, m3, accB.y);
                accB.z = fmaf(v3.z, m3, accB.z); accB.w = fmaf(v3.w, m3, accB.w);
            }
            if (c > 0) {
                float inv = 1.0f / (float)c;
                float4 s;
                s.x = (accA.x + accB.x) * inv;
                s.y = (accA.y + accB.y) * inv;
                s.z = (accA.z + accB.z) * inv;
                s.w = (accA.w + accB.w) * inv;
                msum4[(size_t)node * 16 + sub] = s;   // 256B store per group
            }
        }
    } else {
        // correctness-only path for pathological bucket overflow
        for (int t = 0; t < 16; t++) {
            int lid = w * 16 + t;
            int node = bk * 64 + lid;
            if (node >= N_NODES) break;
            int c = 0;
            float s0 = 0.f;
            for (int j0 = 0; j0 < cntb; j0 += 64) {
                int idx = j0 + lane;
                int p = (idx < cntb) ? binned[base + idx] : -1;
                bool m = (p >= 0) && ((p >> 21) == lid);
                unsigned long long msk = __ballot(m);
                c += __popcll(msk);
                while (msk) {
                    int l = __ffsll((long long)msk) - 1;
                    msk &= msk - 1;
                    int eid = __builtin_amdgcn_readlane(p, l) & 0x1FFFFF;
                    s0 += e[((size_t)eid << 6) + lane];
                }
            }
            if (c > 0) msum[(size_t)node * 64 + lane] = s0 * (1.0f / (float)c);
            if (lane == 0) degOut[node] = c;
        }
    }
}

// ===================== GEMV: msum @ W^T + b (zero for deg==0) =====================
// One wave per 16 consecutive nodes. Stage the wave's 16 mean rows with one
// coalesced 4KB LDS copy, then GEMV against W held in 128 VGPRs via 16 b128
// LDS broadcast reads per node. Streaming: 25.6MB in + 40MB out.
__global__ void __launch_bounds__(256, 2) k_gemv(
        const float* __restrict__ msum, const int* __restrict__ degOut,
        const float* __restrict__ W, const float* __restrict__ b,
        float* __restrict__ out) {
    __shared__ __align__(16) float srow[4][16 * 64];
    int lane = threadIdx.x & 63, w = threadIdx.x >> 6;
    int wave = blockIdx.x * 4 + w;
    int base = wave * 16;
    if (base >= N_NODES) return;               // no barriers below: safe
    int nmax = N_NODES - base;
    if (nmax > 16) nmax = 16;

    int row1 = 64 + lane;
    if (row1 >= OUT_F) row1 = 0;
    float w0[IN_F], w1[IN_F];
    const float4* W4 = (const float4*)W;
    #pragma unroll
    for (int j = 0; j < IN_F / 4; j++) {
        float4 t0 = W4[lane * (IN_F / 4) + j];
        w0[4*j+0] = t0.x; w0[4*j+1] = t0.y; w0[4*j+2] = t0.z; w0[4*j+3] = t0.w;
        float4 t1 = W4[row1 * (IN_F / 4) + j];
        w1[4*j+0] = t1.x; w1[4*j+1] = t1.y; w1[4*j+2] = t1.z; w1[4*j+3] = t1.w;
    }
    float bb0 = b[lane];
    float bb1 = b[row1];

    int d_l = 0;
    if (lane < nmax) d_l = degOut[base + lane];

    float4* s4 = (float4*)&srow[w][0];
    const float4* m4 = (const float4*)msum + (size_t)base * 16;
    int nf4 = nmax * 16;
    #pragma unroll
    for (int it = 0; it < 4; it++) {
        int idx = it * 64 + lane;
        if (idx < nf4) s4[idx] = m4[idx];
    }

    for (int j = 0; j < nmax; j++) {
        int c = __shfl(d_l, j, 64);
        float h0 = 0.0f, h1 = 0.0f;
        if (c > 0) {
            float aa0 = 0.f, aa1 = 0.f;
            const float4* sr4 = (const float4*)&srow[w][j * 64];
            #pragma unroll
            for (int q = 0; q < 16; q++) {
                float4 f = sr4[q];
                aa0 = fmaf(f.x, w0[4*q+0], aa0);  aa1 = fmaf(f.x, w1[4*q+0], aa1);
                aa0 = fmaf(f.y, w0[4*q+1], aa0);  aa1 = fmaf(f.y, w1[4*q+1], aa1);
                aa0 = fmaf(f.z, w0[4*q+2], aa0);  aa1 = fmaf(f.z, w1[4*q+2], aa1);
                aa0 = fmaf(f.w, w0[4*q+3], aa0);  aa1 = fmaf(f.w, w1[4*q+3], aa1);
            }
            h0 = aa0 + bb0;
            h1 = aa1 + bb1;
        }
        int node = base + j;
        size_t ob2 = (size_t)node * OUT_F;
        out[ob2 + lane] = h0;
        if (lane < OUT_F - 64) out[ob2 + 64 + lane] = h1;
    }
}

// ===================== fallback path (atomic-based, < 35.5 MB ws) =====================
__global__ void fb_hist(const int* __restrict__ dst, int* __restrict__ deg) {
    int i = (blockIdx.x * blockDim.x + threadIdx.x) * 4;
    if (i + 3 < N_EDGES) {
        int4 d = *(const int4*)(dst + i);
        atomicAdd(&deg[d.x], 1); atomicAdd(&deg[d.y], 1);
        atomicAdd(&deg[d.z], 1); atomicAdd(&deg[d.w], 1);
    } else {
        for (int k = i; k < N_EDGES; k++) atomicAdd(&deg[dst[k]], 1);
    }
}

__global__ void fb_scan(const int* __restrict__ deg, int* __restrict__ offs,
                        int* __restrict__ cursor, int* __restrict__ gcur) {
    int n = blockIdx.x * blockDim.x + threadIdx.x;
    int lane = threadIdx.x & 63;
    int d = (n < N_NODES) ? deg[n] : 0;
    int x = d;
    #pragma unroll
    for (int off = 1; off < 64; off <<= 1) {
        int y = __shfl_up(x, off, 64);
        if (lane >= off) x += y;
    }
    int excl = x - d;
    int total = __shfl(x, 63, 64);
    int bs = 0;
    if (lane == 63) bs = atomicAdd(gcur, total);
    bs = __shfl(bs, 63, 64);
    if (n < N_NODES) {
        offs[n] = bs + excl;
        cursor[n] = bs + excl;
    }
}

__global__ void fb_scatter(const int* __restrict__ dst, int* __restrict__ cursor,
                           int* __restrict__ eids) {
    int i = (blockIdx.x * blockDim.x + threadIdx.x) * 4;
    if (i + 3 < N_EDGES) {
        int4 d = *(const int4*)(dst + i);
        int p0 = atomicAdd(&cursor[d.x], 1);
        int p1 = atomicAdd(&cursor[d.y], 1);
        int p2 = atomicAdd(&cursor[d.z], 1);
        int p3 = atomicAdd(&cursor[d.w], 1);
        eids[p0] = i; eids[p1] = i + 1; eids[p2] = i + 2; eids[p3] = i + 3;
    } else {
        for (int k = i; k < N_EDGES; k++) {
            int pos = atomicAdd(&cursor[dst[k]], 1);
            eids[pos] = k;
        }
    }
}

__global__ void __launch_bounds__(256) fb_gather(
        const float* __restrict__ e, const int* __restrict__ eids,
        const int* __restrict__ offs, const int* __restrict__ deg,
        const float* __restrict__ W, const float* __restrict__ b,
        float* __restrict__ out, int n_waves_total) {
    __shared__ float srow[4][64];
    int lane = threadIdx.x & 63, w = (threadIdx.x >> 6) & 3;
    int wid  = (blockIdx.x * blockDim.x + threadIdx.x) >> 6;
    int row1 = 64 + lane;
    if (row1 >= OUT_F) row1 = 0;
    float w0[IN_F], w1[IN_F];
    const float4* W4 = (const float4*)W;
    #pragma unroll
    for (int j = 0; j < IN_F / 4; j++) {
        float4 t0 = W4[lane * (IN_F / 4) + j];
        w0[4*j+0] = t0.x; w0[4*j+1] = t0.y; w0[4*j+2] = t0.z; w0[4*j+3] = t0.w;
        float4 t1 = W4[row1 * (IN_F / 4) + j];
        w1[4*j+0] = t1.x; w1[4*j+1] = t1.y; w1[4*j+2] = t1.z; w1[4*j+3] = t1.w;
    }
    float bb0 = b[lane];
    float bb1 = b[row1];
    for (int n = wid; n < N_NODES; n += n_waves_total) {
        int o = __builtin_amdgcn_readfirstlane(offs[n]);
        int c = __builtin_amdgcn_readfirstlane(deg[n]);
        float s0 = 0.f, s1 = 0.f;
        for (int cb = 0; cb < c; cb += 64) {
            int cc = c - cb; if (cc > 64) cc = 64;
            int myeid = 0;
            if (lane < cc) myeid = eids[o + cb + lane];
            for (int j = 0; j < cc; j += 2) {
                int i0 = __builtin_amdgcn_readlane(myeid, j);
                s0 += e[((size_t)i0 << 6) + lane];
                if (j + 1 < cc) {
                    int i1 = __builtin_amdgcn_readlane(myeid, j + 1);
                    s1 += e[((size_t)i1 << 6) + lane];
                }
            }
        }
        float* sr = &srow[w][0];
        sr[lane] = (s0 + s1) * ((c > 0) ? 1.0f / (float)c : 0.0f);
        float a0 = 0.f, a1 = 0.f;
        const float4* sr4 = (const float4*)sr;
        #pragma unroll
        for (int q = 0; q < 16; q++) {
            float4 f = sr4[q];
            a0 = fmaf(f.x, w0[4*q+0], a0);  a1 = fmaf(f.x, w1[4*q+0], a1);
            a0 = fmaf(f.y, w0[4*q+1], a0);  a1 = fmaf(f.y, w1[4*q+1], a1);
            a0 = fmaf(f.z, w0[4*q+2], a0);  a1 = fmaf(f.z, w1[4*q+2], a1);
            a0 = fmaf(f.w, w0[4*q+3], a0);  a1 = fmaf(f.w, w1[4*q+3], a1);
        }
        float h0 = (c > 0) ? a0 + bb0 : 0.0f;
        float h1 = (c > 0) ? a1 + bb1 : 0.0f;
        size_t ob = (size_t)n * OUT_F;
        out[ob + lane] = h0;
        if (lane < OUT_F - 64) out[ob + 64 + lane] = h1;
    }
}

extern "C" void kernel_launch(void* const* d_in, const int* in_sizes, int n_in,
                              void* d_out, int out_size, void* d_ws, size_t ws_size,
                              hipStream_t stream) {
    const float* e   = (const float*)d_in[0];
    const int*   dst = (const int*)d_in[1];
    const float* W   = (const float*)d_in[2];
    const float* b   = (const float*)d_in[3];
    float* out = (float*)d_out;
    char* ws = (char*)d_ws;

    if (ws_size >= WS_NEEDED) {
        int*   cnt    = (int*)(ws + OFF_CNT);
        int*   part   = (int*)(ws + OFF_PART);
        int*   binned = (int*)(ws + OFF_BIN);
        float* msum   = (float*)(ws + OFF_MSUM);
        int*   degOut = (int*)(ws + OFF_DEGO);

        k_count<<<NBLK, 256, 0, stream>>>(dst, cnt);
        k_s1   <<<SB, 256, 0, stream>>>(cnt, part);
        k_s2   <<<1, 64, 0, stream>>>(part);
        k_s3   <<<SB, 256, 0, stream>>>(cnt, part);
        k_bin  <<<NBLK, 256, 0, stream>>>(dst, cnt, binned);
        k_gsum <<<K_BUCKETS, 256, 0, stream>>>(e, binned, cnt, msum, degOut);
        k_gemv <<<(N_NODES / 16 + 3) / 4 + 1, 256, 0, stream>>>(msum, degOut, W, b, out);
    } else {
        int* deg    = (int*)(ws + FB_DEG);
        int* offs   = (int*)(ws + FB_OFFS);
        int* cursor = (int*)(ws + FB_CURSOR);
        int* gcur   = (int*)(ws + FB_GCUR);
        int* eids   = (int*)(ws + FB_EIDS);

        hipMemsetAsync(deg, 0, N_NODES * sizeof(int), stream);
        hipMemsetAsync(gcur, 0, sizeof(int), stream);
        fb_hist   <<<(N_EDGES / 4 + 255) / 256, 256, 0, stream>>>(dst, deg);
        fb_scan   <<<(N_NODES + 255) / 256, 256, 0, stream>>>(deg, offs, cursor, gcur);
        fb_scatter<<<(N_EDGES / 4 + 255) / 256, 256, 0, stream>>>(dst, cursor, eids);
        fb_gather <<<8192, 256, 0, stream>>>(e, eids, offs, deg, W, b, out, 8192 * 4);
    }
}